// Round 2
// baseline (243.511 us; speedup 1.0000x reference)
//
#include <hip/hip_runtime.h>
#include <hip/hip_bf16.h>

typedef float f32x4 __attribute__((ext_vector_type(4)));
typedef short s16x8 __attribute__((ext_vector_type(8)));

#define NPIX       12544      // B*nH*nW = 16*28*28
#define TPLANE     802816     // NPIX*64 floats per t-plane
#define OUT_STRIDE 12845056   // 16*112*112*64 elements per stream output

__device__ __forceinline__ unsigned short f2bf(float x) {
    union { float f; unsigned u; } un; un.f = x;
    unsigned r = un.u + 0x7FFFu + ((un.u >> 16) & 1u);  // RNE
    return (unsigned short)(r >> 16);
}

__device__ __forceinline__ short bfs(float x) {
    __hip_bfloat16 h = __float2bfloat16(x);             // RNE; may fuse to v_cvt_pk_bf16_f32
    return *reinterpret_cast<short*>(&h);
}

// Repack weights fp32 -> bf16 MFMA B-fragments in d_ws, scaled by 1/16.
// Coalesced linear read of w, scattered 2B writes (L2 absorbs).
// Fragment (lane,e) = w[t][c = ks*32 + (lane>>4)*8 + e][k = nt*16 + (lane&15)] / 16
// stored at granule index (((s*16+t)*2+ks)*4+nt)*64+lane, element e.
__global__ __launch_bounds__(256) void repack_weights(
        const float* __restrict__ w1, const float* __restrict__ w2,
        unsigned short* __restrict__ wf) {
    int gid = blockIdx.x * 256 + threadIdx.x;   // [s][t][c][k], k fastest
    int k = gid & 63;
    int c = (gid >> 6) & 63;
    int t = (gid >> 12) & 15;
    int s = (gid >> 16) & 1;
    const float* __restrict__ w = s ? w2 : w1;
    float val = w[gid & 65535] * 0.0625f;
    int e = c & 7, lhi = (c >> 3) & 3, ks = c >> 5;
    int l  = lhi * 16 + (k & 15);
    int nt = k >> 4;
    int dst = ((((s * 16 + t) * 2 + ks) * 4 + nt) * 64 + l) * 8 + e;
    wf[dst] = f2bf(val);
}

// Block: 256 threads = 4 waves, no LDS, no barriers.
// Wave `wid` owns k-tile [wid*16, wid*16+16); all 4 waves stream the same
// 16-pixel A rows straight from global (L1-resident re-reads).
__global__ __launch_bounds__(256, 4) void iwht_main(
        const float* __restrict__ trans1, const float* __restrict__ trans2,
        const unsigned short* __restrict__ wf,
        const float* __restrict__ bias1, const float* __restrict__ bias2,
        float* __restrict__ out) {
    const int tid = threadIdx.x;
    const int bid = blockIdx.x;   // 0..783
    const int s   = blockIdx.y;   // stream 0/1

    const int wid  = tid >> 6;
    const int lane = tid & 63;
    const int lrow = lane & 15;
    const int lhi  = lane >> 4;

    const float* __restrict__ trans = s ? trans2 : trans1;
    const float* __restrict__ bias  = s ? bias2  : bias1;

    // per-lane A base: pixel (bid*16 + lrow), channel lhi*8
    const f32x4* __restrict__ abase =
        (const f32x4*)(trans + ((size_t)(bid * 16 + lrow)) * 64 + lhi * 8);

    // B fragments: granule stride per t = 512, ks=1 adds 256
    const s16x8* __restrict__ wb =
        (const s16x8*)wf + (size_t)s * 8192 + wid * 64 + lane;

    f32x4 o[4][4];
    #pragma unroll
    for (int i = 0; i < 4; ++i)
        #pragma unroll
        for (int j = 0; j < 4; ++j)
            o[i][j] = (f32x4){0.f, 0.f, 0.f, 0.f};

    #pragma unroll 1
    for (int u = 0; u < 4; ++u) {
        // issue all 16 A-loads for this u-group first (vmcnt-pipelined)
        f32x4 st[4][4];
        #pragma unroll
        for (int v = 0; v < 4; ++v) {
            const int t = u * 4 + v;
            const f32x4* ap = abase + (size_t)t * (TPLANE / 4);
            st[v][0] = ap[0];   // c = lhi*8 + 0..3
            st[v][1] = ap[1];   // c = lhi*8 + 4..7
            st[v][2] = ap[8];   // c = 32 + lhi*8 + 0..3
            st[v][3] = ap[9];   // c = 32 + lhi*8 + 4..7
        }
        f32x4 g0 = {0.f,0.f,0.f,0.f}, g1 = {0.f,0.f,0.f,0.f};
        f32x4 g2 = {0.f,0.f,0.f,0.f}, g3 = {0.f,0.f,0.f,0.f};
        #pragma unroll
        for (int v = 0; v < 4; ++v) {
            const int t = u * 4 + v;
            s16x8 a0, a1;
            #pragma unroll
            for (int e = 0; e < 4; ++e) {
                a0[e]     = bfs(st[v][0][e]);
                a0[e + 4] = bfs(st[v][1][e]);
                a1[e]     = bfs(st[v][2][e]);
                a1[e + 4] = bfs(st[v][3][e]);
            }
            s16x8 b0 = wb[t * 512];
            s16x8 b1 = wb[t * 512 + 256];
            f32x4 acc = {0.f, 0.f, 0.f, 0.f};
            acc = __builtin_amdgcn_mfma_f32_16x16x32_bf16(a0, b0, acc, 0, 0, 0);
            acc = __builtin_amdgcn_mfma_f32_16x16x32_bf16(a1, b1, acc, 0, 0, 0);
            // v-transform: g[j] += H4[j][v] * acc  (signs static per v)
            g0 += acc;
            if (v == 0) { g1 += acc; g2 += acc; g3 += acc; }
            if (v == 1) { g1 -= acc; g2 += acc; g3 -= acc; }
            if (v == 2) { g1 += acc; g2 -= acc; g3 -= acc; }
            if (v == 3) { g1 -= acc; g2 -= acc; g3 += acc; }
        }
        // u-transform fold: o[i][j] += H4[i][u] * g[j]  (signs wave-uniform)
        const float s1 = (u & 1) ? -1.f : 1.f;
        const float s2 = (u & 2) ? -1.f : 1.f;
        const float s3 = s1 * s2;
        #pragma unroll
        for (int j = 0; j < 4; ++j) {
            f32x4 gj = (j == 0) ? g0 : ((j == 1) ? g1 : ((j == 2) ? g2 : g3));
            o[0][j] += gj;
            o[1][j] += s1 * gj;
            o[2][j] += s2 * gj;
            o[3][j] += s3 * gj;
        }
    }

    // ---------------- epilogue: bias + scatter-store ----------------
    const int k  = wid * 16 + lrow;         // C/D col = lane&15
    const float bk = bias[k];
    const int bimg = bid / 49;              // 49 blocks per image
    const int hw0  = (bid % 49) * 16;
    float* __restrict__ outp = out + (s ? (size_t)OUT_STRIDE : 0);

    size_t rbase[4];
    #pragma unroll
    for (int r = 0; r < 4; ++r) {           // C/D row = lhi*4 + r (pixel)
        int hw = hw0 + lhi * 4 + r;
        int h = hw / 28, w = hw % 28;
        rbase[r] = ((size_t)(bimg * 112 + h * 4) * 112 + (w * 4)) * 64 + k;
    }
    #pragma unroll
    for (int i = 0; i < 4; ++i)
        #pragma unroll
        for (int j = 0; j < 4; ++j) {
            #pragma unroll
            for (int r = 0; r < 4; ++r)
                outp[rbase[r] + (size_t)((i * 112 + j) * 64)] = o[i][j][r] + bk;
        }
}

extern "C" void kernel_launch(void* const* d_in, const int* in_sizes, int n_in,
                              void* d_out, int out_size, void* d_ws, size_t ws_size,
                              hipStream_t stream) {
    const float* t1 = (const float*)d_in[0];
    const float* t2 = (const float*)d_in[1];
    const float* w1 = (const float*)d_in[2];
    const float* w2 = (const float*)d_in[3];
    const float* b1 = (const float*)d_in[4];
    const float* b2 = (const float*)d_in[5];
    unsigned short* wfrag = (unsigned short*)d_ws;   // 256 KB of bf16 fragments
    float* out = (float*)d_out;

    repack_weights<<<dim3(512), dim3(256), 0, stream>>>(w1, w2, wfrag);
    iwht_main<<<dim3(784, 2), dim3(256), 0, stream>>>(t1, t2, wfrag, b1, b2, out);
}

// Round 3
// 202.721 us; speedup vs baseline: 1.2012x; 1.2012x over previous
//
#include <hip/hip_runtime.h>
#include <hip/hip_bf16.h>

typedef float f32x4 __attribute__((ext_vector_type(4)));
typedef short s16x8 __attribute__((ext_vector_type(8)));

#define NPIX       12544      // B*nH*nW = 16*28*28
#define OUT_STRIDE 12845056   // 16*112*112*64 elements per stream output
#define NTILES     1568       // 784 pixel-groups x 2 streams
#define GRIDX      512        // 2 blocks/CU

__device__ __forceinline__ unsigned short f2bf(float x) {
    union { float f; unsigned u; } un; un.f = x;
    unsigned r = un.u + 0x7FFFu + ((un.u >> 16) & 1u);  // RNE
    return (unsigned short)(r >> 16);
}

__device__ __forceinline__ short bfs(float x) {
    __hip_bfloat16 h = __float2bfloat16(x);
    return *reinterpret_cast<short*>(&h);
}

__device__ __forceinline__ void gload_lds16(const void* g, void* l) {
    __builtin_amdgcn_global_load_lds(
        (const __attribute__((address_space(1))) unsigned int*)g,
        (__attribute__((address_space(3))) unsigned int*)l, 16, 0, 0);
}

// Repack weights fp32 -> bf16 MFMA B-fragments in d_ws, scaled by 1/16.
// Fragment (lane,e) = w[t][c = ks*32 + (lane>>4)*8 + e][k = nt*16 + (lane&15)] / 16
// at granule (((s*16+t)*2+ks)*4+nt)*64+lane, element e.
__global__ __launch_bounds__(256) void repack_weights(
        const float* __restrict__ w1, const float* __restrict__ w2,
        unsigned short* __restrict__ wf) {
    int gid = blockIdx.x * 256 + threadIdx.x;   // [s][t][c][k], k fastest
    int k = gid & 63;
    int c = (gid >> 6) & 63;
    int t = (gid >> 12) & 15;
    int s = (gid >> 16) & 1;
    const float* __restrict__ w = s ? w2 : w1;
    float val = w[gid & 65535] * 0.0625f;
    int e = c & 7, lhi = (c >> 3) & 3, ks = c >> 5;
    int l  = lhi * 16 + (k & 15);
    int nt = k >> 4;
    int dst = ((((s * 16 + t) * 2 + ks) * 4 + nt) * 64 + l) * 8 + e;
    wf[dst] = f2bf(val);
}

// Persistent: each block loops over tiles (16 pixels x 1 stream).
// A staged fp32 via global_load_lds into granule layout t*256 + q*64 + lane
// (q = ks*2+j staged by wave wid=q, per-lane pre-swizzled global source).
__global__ __launch_bounds__(256, 2) void iwht_main(
        const float* __restrict__ trans1, const float* __restrict__ trans2,
        const unsigned short* __restrict__ wf,
        const float* __restrict__ bias1, const float* __restrict__ bias2,
        float* __restrict__ out) {
    __shared__ __align__(16) unsigned char lds[65536];

    const int tid  = threadIdx.x;
    const int wid  = tid >> 6;
    const int lane = tid & 63;
    const int lrow = lane & 15;   // pixel-in-tile / MFMA row
    const int lhi  = lane >> 4;

    const s16x8* __restrict__ wbb = (const s16x8*)wf;

    for (int tau = blockIdx.x; tau < NTILES; tau += GRIDX) {
        const int s   = (tau >= 784) ? 1 : 0;
        const int bid = tau - s * 784;
        const float* __restrict__ trans = s ? trans2 : trans1;
        const int p0 = bid * 16;

        // ---- issue async staging: 16 gl_lds per wave (q = wid) ----
        {
            const int ks = wid >> 1, j = wid & 1;
            const float* g0 = trans + (size_t)(p0 + lrow) * 64
                                    + (ks * 8 + lhi * 2 + j) * 4;  // per-lane src
            #pragma unroll
            for (int t = 0; t < 16; ++t)
                gload_lds16(g0 + (size_t)t * (NPIX * 64),
                            lds + t * 4096 + wid * 1024);   // uniform base; +lane*16 by HW
        }

        // ---- prefetch B for u=0 (issued before the barrier's vmcnt drain) ----
        const s16x8* __restrict__ wb = wbb + (size_t)s * 8192 + wid * 64 + lane;
        s16x8 bA[8], bB[8];   // [ks*4 + v]
        #pragma unroll
        for (int v = 0; v < 4; ++v) {
            bA[v]     = wb[(size_t)(v * 8 + 0) * 64];
            bA[4 + v] = wb[(size_t)(v * 8 + 4) * 64];
        }

        f32x4 o[4][4];
        #pragma unroll
        for (int i = 0; i < 4; ++i)
            #pragma unroll
            for (int j = 0; j < 4; ++j)
                o[i][j] = (f32x4){0.f, 0.f, 0.f, 0.f};

        __syncthreads();   // implicit s_waitcnt vmcnt(0): staging + bA landed

        #pragma unroll 1
        for (int uu = 0; uu < 4; uu += 2) {
            // -------- u = uu (uses bA); prefetch bB for u+1 --------
            #pragma unroll
            for (int v = 0; v < 4; ++v) {
                int t = (uu + 1) * 4 + v;
                bB[v]     = wb[(size_t)(t * 8 + 0) * 64];
                bB[4 + v] = wb[(size_t)(t * 8 + 4) * 64];
            }
            #pragma unroll
            for (int half = 0; half < 2; ++half) {
                const int u = uu + half;
                f32x4 acc[4];
                #pragma unroll
                for (int v = 0; v < 4; ++v) {
                    const int t = u * 4 + v;
                    const unsigned char* ab = lds + t * 4096 + lane * 16;
                    f32x4 q0 = *(const f32x4*)(ab);          // c[lhi*8 + 0..3]
                    f32x4 q1 = *(const f32x4*)(ab + 1024);   // c[lhi*8 + 4..7]
                    f32x4 q2 = *(const f32x4*)(ab + 2048);   // c[32+lhi*8 + 0..3]
                    f32x4 q3 = *(const f32x4*)(ab + 3072);   // c[32+lhi*8 + 4..7]
                    s16x8 a0, a1;
                    #pragma unroll
                    for (int e = 0; e < 4; ++e) {
                        a0[e] = bfs(q0[e]); a0[4 + e] = bfs(q1[e]);
                        a1[e] = bfs(q2[e]); a1[4 + e] = bfs(q3[e]);
                    }
                    f32x4 tacc = {0.f, 0.f, 0.f, 0.f};
                    if (half == 0) {
                        tacc = __builtin_amdgcn_mfma_f32_16x16x32_bf16(a0, bA[v],     tacc, 0, 0, 0);
                        tacc = __builtin_amdgcn_mfma_f32_16x16x32_bf16(a1, bA[4 + v], tacc, 0, 0, 0);
                    } else {
                        tacc = __builtin_amdgcn_mfma_f32_16x16x32_bf16(a0, bB[v],     tacc, 0, 0, 0);
                        tacc = __builtin_amdgcn_mfma_f32_16x16x32_bf16(a1, bB[4 + v], tacc, 0, 0, 0);
                    }
                    acc[v] = tacc;
                }
                if (half == 0 && uu + 2 < 4) {   // prefetch bA for u=2
                    #pragma unroll
                    for (int v = 0; v < 4; ++v) {
                        int t = (uu + 2) * 4 + v;
                        bA[v]     = wb[(size_t)(t * 8 + 0) * 64];
                        bA[4 + v] = wb[(size_t)(t * 8 + 4) * 64];
                    }
                }
                // v-butterfly: g[j] = sum_v H4[j][v] acc[v]
                f32x4 e0 = acc[0] + acc[1], e1 = acc[0] - acc[1];
                f32x4 e2 = acc[2] + acc[3], e3 = acc[2] - acc[3];
                f32x4 g0 = e0 + e2, g1 = e1 + e3, g2 = e0 - e2, g3 = e1 - e3;
                const float s1 = (u & 1) ? -1.f : 1.f;
                const float s2 = (u & 2) ? -1.f : 1.f;
                const float s3 = s1 * s2;
                #pragma unroll
                for (int j = 0; j < 4; ++j) {
                    f32x4 gj = (j == 0) ? g0 : ((j == 1) ? g1 : ((j == 2) ? g2 : g3));
                    o[0][j] += gj;
                    o[1][j] += s1 * gj;
                    o[2][j] += s2 * gj;
                    o[3][j] += s3 * gj;
                }
            }
        }

        // ---- epilogue: bias + LDS transpose + coalesced row stores ----
        const float* __restrict__ bias = s ? bias2 : bias1;
        const int k = wid * 16 + lrow;
        const float bk = bias[k];
        __syncthreads();   // all A reads done; LDS becomes out-stage
        #pragma unroll
        for (int i = 0; i < 4; ++i)
            #pragma unroll
            for (int j = 0; j < 4; ++j)
                #pragma unroll
                for (int r = 0; r < 4; ++r) {
                    int p = lhi * 4 + r;
                    int w = k ^ (4 * (p & 7)) ^ (16 * (j & 1));   // XOR-swizzle: 2-way write
                    *(float*)(lds + p * 4096 + i * 1024 + j * 256 + w * 4) = o[i][j][r] + bk;
                }
        __syncthreads();
        const int bimg = bid / 49;
        const int hw0  = (bid % 49) * 16;
        float* __restrict__ outp = out + (s ? (size_t)OUT_STRIDE : 0);
        #pragma unroll
        for (int n = 0; n < 16; ++n) {
            int idx = wid * 16 + n;
            int p = idx >> 2, i = idx & 3;
            int hw = hw0 + p;
            int h = hw / 28, w = hw % 28;
            size_t rowbase = ((size_t)(bimg * 112 + h * 4 + i) * 112 + w * 4) * 64;
            int g = (lane & 15) ^ (p & 7) ^ (4 * ((lane >> 4) & 1));
            f32x4 val = *(const f32x4*)(lds + p * 4096 + i * 1024
                                        + (lane >> 4) * 256 + g * 16);
            *(f32x4*)(outp + rowbase + lane * 4) = val;   // 1 KB/wave contiguous
        }
        __syncthreads();   // protect LDS before next tile's gl_lds
    }
}

extern "C" void kernel_launch(void* const* d_in, const int* in_sizes, int n_in,
                              void* d_out, int out_size, void* d_ws, size_t ws_size,
                              hipStream_t stream) {
    const float* t1 = (const float*)d_in[0];
    const float* t2 = (const float*)d_in[1];
    const float* w1 = (const float*)d_in[2];
    const float* w2 = (const float*)d_in[3];
    const float* b1 = (const float*)d_in[4];
    const float* b2 = (const float*)d_in[5];
    unsigned short* wfrag = (unsigned short*)d_ws;   // 256 KB bf16 fragments
    float* out = (float*)d_out;

    repack_weights<<<dim3(512), dim3(256), 0, stream>>>(w1, w2, wfrag);
    iwht_main<<<dim3(GRIDX), dim3(256), 0, stream>>>(t1, t2, wfrag, b1, b2, out);
}